// Round 14
// baseline (46.555 us; speedup 1.0000x reference)
//
#include <hip/hip_runtime.h>

// Chamfer (bidirectional 1-NN mean of squared distances), two [16384,3] fp32 clouds.
// Round-14: ONE-PASS row+col mins. R7-R13 computed the 16384^2 distance matrix
// TWICE (dir1 = transpose). Seven structural variants were all ~30us => time
// tracks total work, so halve the work: a single pass over D[i][j] = dist(P0_i,
// P1_j) accumulates row-mins (dir0, registers as before) AND col-mins (dir1):
// per 32x32 tile, col-min = min over 16 regs of both A-frag results (cols are
// lane&31; lanes l and l+32 hold disjoint row-halves) + shfl_xor(32), merged via
// LDS atomicMin per block, then one global atomicMin per col per block.
// All merges use uint-bit atomicMin on clamped (>=0) values -> deterministic.
//
// MFMA formulation (one v_mfma_f32_32x32x16_f16 per 32x32 distance tile):
//   x = xh + xl (split fp16). K slots:
//     0..2 A=-2a_hi B=b_hi | 3..5 A=-2a_hi B=b_lo | 6..8 A=-2a_lo B=b_hi
//     9,10 A={a2_hi,a2_lo} B={1,1} | 11,12 A={1,1} B={b2_hi,b2_lo} | 13..15 zero
//   => D[i][j] = a2 + b2 - 2 a.b + O(3e-3), fp32 accumulators. (absmax 0.0 since R7)
// C/D layout (verified): col=lane&31, row=(reg&3)+8*(reg>>2)+4*(lane>>5).

typedef _Float16 half8 __attribute__((ext_vector_type(8)));
typedef float floatx16 __attribute__((ext_vector_type(16)));

#define NPTS 16384
#define BLOCK 256
#define WAVES 4
#define TILE 32
#define ROWSW (2 * TILE)              // 64 A-rows per wave (2 fragments)
#define APB (WAVES * ROWSW)           // 256 A-points per block
#define NBSPLIT 16
#define BSWEEP (NPTS / NBSPLIT)       // 1024 B-points per block
#define NTILES (BSWEEP / TILE)        // 32 B-tiles per block

union H8 { _Float16 h[8]; uint4 u; };

// P0 -> A-format fragments, P1 -> B-format fragments (32 B/point each);
// also initialize the partial-min array (2*NPTS u32).
__global__ __launch_bounds__(256) void prep_kernel(
    const float* __restrict__ P0, const float* __restrict__ P1,
    uint4* __restrict__ Ap, uint4* __restrict__ Bp,
    unsigned* __restrict__ dmin_all)
{
    const int i = blockIdx.x * 256 + threadIdx.x;      // 0..2*NPTS-1
    dmin_all[i] = 0x7F7F7F7Fu;                         // 3.39e38 > any real distance

    const bool isA = (i < NPTS);
    const float* P = isA ? P0 : P1;
    const int k = isA ? i : i - NPTS;
    const float x = P[k * 3 + 0], y = P[k * 3 + 1], z = P[k * 3 + 2];
    const float q2 = x * x + y * y + z * z;

    const _Float16 xh = (_Float16)x; const float xl = x - (float)xh;
    const _Float16 yh = (_Float16)y; const float yl = y - (float)yh;
    const _Float16 zh = (_Float16)z; const float zl = z - (float)zh;
    const _Float16 qh = (_Float16)q2; const float ql = q2 - (float)qh;
    const _Float16 one = (_Float16)1.0f, zero = (_Float16)0.0f;

    if (isA) {
        H8 a0, a1;
        a0.h[0] = (_Float16)(-2.0f * (float)xh);
        a0.h[1] = (_Float16)(-2.0f * (float)yh);
        a0.h[2] = (_Float16)(-2.0f * (float)zh);
        a0.h[3] = a0.h[0]; a0.h[4] = a0.h[1]; a0.h[5] = a0.h[2];
        a0.h[6] = (_Float16)(-2.0f * xl);
        a0.h[7] = (_Float16)(-2.0f * yl);
        a1.h[0] = (_Float16)(-2.0f * zl);
        a1.h[1] = qh; a1.h[2] = (_Float16)ql;
        a1.h[3] = one; a1.h[4] = one;
        a1.h[5] = zero; a1.h[6] = zero; a1.h[7] = zero;
        Ap[(size_t)k * 2 + 0] = a0.u; Ap[(size_t)k * 2 + 1] = a1.u;
    } else {
        H8 b0, b1;
        b0.h[0] = xh; b0.h[1] = yh; b0.h[2] = zh;
        b0.h[3] = (_Float16)xl; b0.h[4] = (_Float16)yl; b0.h[5] = (_Float16)zl;
        b0.h[6] = xh; b0.h[7] = yh;
        b1.h[0] = zh; b1.h[1] = one; b1.h[2] = one;
        b1.h[3] = qh; b1.h[4] = (_Float16)ql;
        b1.h[5] = zero; b1.h[6] = zero; b1.h[7] = zero;
        Bp[(size_t)k * 2 + 0] = b0.u; Bp[(size_t)k * 2 + 1] = b1.u;
    }
}

#define MF(afx, bf) __builtin_amdgcn_mfma_f32_32x32x16_f16((afx), (bf), ZC, 0, 0, 0)

__global__ __launch_bounds__(BLOCK, 4) void chamfer_mfma(
    const uint4* __restrict__ Ap, const uint4* __restrict__ Bp,
    unsigned* __restrict__ dmin_all)
{
    __shared__ unsigned scmin[BSWEEP];   // block-level col-min accumulator (4 KB)

    const int tid  = threadIdx.x;
    const int lane = tid & 63;
    const int wid  = tid >> 6;
    const int half = lane >> 5;
    const int lj   = lane & 31;

    // Init block col-min array.
    for (int i = tid; i < BSWEEP; i += BLOCK) scmin[i] = 0x7F7F7F7Fu;
    __syncthreads();

    const int arow0 = blockIdx.x * APB + wid * ROWSW;

    // Two A fragments per wave (rows arow0+lj, arow0+32+lj).
    const half8 af0 = *reinterpret_cast<const half8*>(
        &Ap[((size_t)(arow0 + lj)) * 2 + half]);
    const half8 af1 = *reinterpret_cast<const half8*>(
        &Ap[((size_t)(arow0 + 32 + lj)) * 2 + half]);

    const floatx16 ZC = (floatx16)(0.0f);

    float rmin0[16], rmin1[16];
#pragma unroll
    for (int r = 0; r < 16; ++r) { rmin0[r] = 3.0e38f; rmin1[r] = 3.0e38f; }

    const int bbase = blockIdx.y * BSWEEP;
    const uint4* Bc = Bp + (size_t)bbase * 2;

    // One pass: per B-fragment, 2 MFMAs (both A-frags), row-min into registers,
    // col-min tree + cross-half shuffle + LDS atomic. B read direct from L2.
#pragma unroll 2
    for (int t = 0; t < NTILES; ++t) {
        const half8 bf = *reinterpret_cast<const half8*>(
            &Bc[(size_t)(t * TILE + lj) * 2 + half]);
        const floatx16 dA = MF(af0, bf);
        const floatx16 dB = MF(af1, bf);
        // row mins (this wave's 64 rows)
#pragma unroll
        for (int r = 0; r < 16; ++r) {
            rmin0[r] = fminf(dA[r], rmin0[r]);
            rmin1[r] = fminf(dB[r], rmin1[r]);
        }
        // col min over this wave's 64 rows for the tile's 32 cols
        float c = fminf(dA[0], dB[0]);
#pragma unroll
        for (int r = 1; r < 16; ++r) c = fminf(fminf(dA[r], dB[r]), c);  // v_min3
        c = fminf(c, __shfl_xor(c, 32, 64));   // combine row-halves (same col)
        if (lane < 32)
            atomicMin(&scmin[t * TILE + lj], __float_as_uint(fmaxf(c, 0.0f)));
    }

    // Row-side: butterfly over the 32 lanes sharing each row set, then merge.
#pragma unroll
    for (int r = 0; r < 16; ++r) {
        float v0 = rmin0[r];
        v0 = fminf(v0, __shfl_xor(v0, 1, 32));
        v0 = fminf(v0, __shfl_xor(v0, 2, 32));
        v0 = fminf(v0, __shfl_xor(v0, 4, 32));
        v0 = fminf(v0, __shfl_xor(v0, 8, 32));
        v0 = fminf(v0, __shfl_xor(v0, 16, 32));
        rmin0[r] = v0;
        float v1 = rmin1[r];
        v1 = fminf(v1, __shfl_xor(v1, 1, 32));
        v1 = fminf(v1, __shfl_xor(v1, 2, 32));
        v1 = fminf(v1, __shfl_xor(v1, 4, 32));
        v1 = fminf(v1, __shfl_xor(v1, 8, 32));
        v1 = fminf(v1, __shfl_xor(v1, 16, 32));
        rmin1[r] = v1;
    }
    if (lj == 0) {
#pragma unroll
        for (int r = 0; r < 16; ++r) {
            const int row = (r & 3) + 8 * (r >> 2) + 4 * half;
            atomicMin(&dmin_all[arow0 + row],
                      __float_as_uint(fmaxf(rmin0[r], 0.0f)));
            atomicMin(&dmin_all[arow0 + 32 + row],
                      __float_as_uint(fmaxf(rmin1[r], 0.0f)));
        }
    }

    // Col-side: block's col-mins -> global (dir1 slots), one atomic per col.
    __syncthreads();
    for (int i = tid; i < BSWEEP; i += BLOCK)
        atomicMin(&dmin_all[NPTS + bbase + i], scmin[i]);
}

__global__ __launch_bounds__(1024) void chamfer_reduce_kernel(
    const unsigned* __restrict__ dmin_all, float* __restrict__ out)
{
    __shared__ double sdata[1024];
    double s = 0.0;
    for (int i = threadIdx.x; i < 2 * NPTS; i += 1024)
        s += (double)__uint_as_float(dmin_all[i]);
    sdata[threadIdx.x] = s;
    __syncthreads();
    for (int off = 512; off > 0; off >>= 1) {
        if (threadIdx.x < off) sdata[threadIdx.x] += sdata[threadIdx.x + off];
        __syncthreads();
    }
    if (threadIdx.x == 0) out[0] = (float)(sdata[0] / (double)NPTS);
}

extern "C" void kernel_launch(void* const* d_in, const int* in_sizes, int n_in,
                              void* d_out, int out_size, void* d_ws, size_t ws_size,
                              hipStream_t stream)
{
    const float* P0 = (const float*)d_in[0];
    const float* P1 = (const float*)d_in[1];
    float* out = (float*)d_out;

    unsigned* dmin = (unsigned*)d_ws;                                     // 128 KB
    uint4* Ap = (uint4*)((char*)d_ws + 2 * NPTS * sizeof(unsigned));      // 512 KB
    uint4* Bp = Ap + (size_t)NPTS * 2;                                    // 512 KB

    prep_kernel<<<(2 * NPTS) / 256, 256, 0, stream>>>(P0, P1, Ap, Bp, dmin);

    dim3 grid(NPTS / APB, NBSPLIT);   // 64 x 16 = 1024 blocks, 4 blocks/CU
    chamfer_mfma<<<grid, BLOCK, 0, stream>>>(Ap, Bp, dmin);

    chamfer_reduce_kernel<<<1, 1024, 0, stream>>>(dmin, out);
}